// Round 15
// baseline (941.517 us; speedup 1.0000x reference)
//
#include <hip/hip_runtime.h>
#include <math.h>

#define NHEAD 4
#define CCH 128
#define HCD 512
#define SLOPE 0.2f
#define EPS_BN 1e-5f

typedef short s8v __attribute__((ext_vector_type(8)));
typedef float f32x4 __attribute__((ext_vector_type(4)));

// RNE f32 -> bf16 (finite values), and back
__device__ __forceinline__ unsigned short f2bf(float f) {
    unsigned int u = __float_as_uint(f);
    return (unsigned short)((u + 0x7FFFu + ((u >> 16) & 1u)) >> 16);
}
__device__ __forceinline__ float bf2f(unsigned short b) {
    return __uint_as_float(((unsigned int)b) << 16);
}

// ---- layer 1 node transforms: x[N,9] @ W[9,512] + b, both l and r ----
__global__ void lin1_kernel(const float* __restrict__ x,
                            const float* __restrict__ Wl, const float* __restrict__ bl,
                            const float* __restrict__ Wr, const float* __restrict__ br,
                            float* __restrict__ xl, float* __restrict__ xr, int n) {
    int gid = blockIdx.x * blockDim.x + threadIdx.x;
    if (gid >= n * HCD) return;
    int node = gid >> 9;
    int c = gid & (HCD - 1);
    const float* xrow = x + node * 9;
    float a = bl[c], bz = br[c];
#pragma unroll
    for (int k = 0; k < 9; ++k) {
        float xv = xrow[k];
        a  = fmaf(xv, Wl[k * HCD + c], a);
        bz = fmaf(xv, Wr[k * HCD + c], bz);
    }
    xl[gid] = a;
    xr[gid] = bz;
}

// ---- split A = relu(bn(h)) into bf16 hi/lo, row-major [n][512] ----
__global__ void splitA_kernel(const float* __restrict__ h,
                              const float* __restrict__ scale, const float* __restrict__ shift,
                              unsigned short* __restrict__ Ah, unsigned short* __restrict__ Al,
                              int total4) {
    int gid = blockIdx.x * blockDim.x + threadIdx.x;
    if (gid >= total4) return;
    int c4 = gid & 127;
    float4 v = ((const float4*)h)[gid];
    float4 sc = ((const float4*)scale)[c4];
    float4 sh = ((const float4*)shift)[c4];
    float f0 = fmaxf(fmaf(v.x, sc.x, sh.x), 0.f);
    float f1 = fmaxf(fmaf(v.y, sc.y, sh.y), 0.f);
    float f2 = fmaxf(fmaf(v.z, sc.z, sh.z), 0.f);
    float f3 = fmaxf(fmaf(v.w, sc.w, sh.w), 0.f);
    unsigned short h0 = f2bf(f0), h1 = f2bf(f1), h2 = f2bf(f2), h3 = f2bf(f3);
    short4 hv = make_short4((short)h0, (short)h1, (short)h2, (short)h3);
    short4 lv = make_short4((short)f2bf(f0 - bf2f(h0)), (short)f2bf(f1 - bf2f(h1)),
                            (short)f2bf(f2 - bf2f(h2)), (short)f2bf(f3 - bf2f(h3)));
    ((short4*)Ah)[gid] = hv;
    ((short4*)Al)[gid] = lv;
}

// ---- split + transpose W[k][col] -> BT[col][k] bf16 hi/lo, both matrices ----
__global__ void splitBT_kernel(const float* __restrict__ Wl, const float* __restrict__ Wr,
                               unsigned short* __restrict__ BThl, unsigned short* __restrict__ BTll,
                               unsigned short* __restrict__ BThr, unsigned short* __restrict__ BTlr) {
    int gid = blockIdx.x * blockDim.x + threadIdx.x;   // 512*512
    int col = gid >> 9;
    int k = gid & 511;
    float vl = Wl[k * HCD + col];
    float vr = Wr[k * HCD + col];
    unsigned short hl = f2bf(vl);
    unsigned short hr = f2bf(vr);
    BThl[gid] = hl; BTll[gid] = f2bf(vl - bf2f(hl));
    BThr[gid] = hr; BTlr[gid] = f2bf(vr - bf2f(hr));
}

// ---- split-bf16 MFMA GEMM, LDS double-buffered (1 barrier/k-step), XCD-swizzled ----
__global__ __launch_bounds__(256) void gemm_mfma_kernel(
        const unsigned short* __restrict__ Ah, const unsigned short* __restrict__ Al,
        const unsigned short* __restrict__ BThL, const unsigned short* __restrict__ BTlL,
        const unsigned short* __restrict__ BThR, const unsigned short* __restrict__ BTlR,
        const float* __restrict__ biasl, const float* __restrict__ biasr,
        float* __restrict__ outL, float* __restrict__ outR, int M) {
    __shared__ short sAh[2][4096], sAl[2][4096], sBh[2][4096], sBl[2][4096];  // 64 KB
    const int nrt = gridDim.x >> 3;
    const int bphys = blockIdx.x;
    const int l = (bphys & 7) * nrt + (bphys >> 3);
    const int y = l & 7;
    const int row0 = (l >> 3) * 128;
    const unsigned short* BTh = (y < 4) ? BThL : BThR;
    const unsigned short* BTl = (y < 4) ? BTlL : BTlR;
    const float* bias = (y < 4) ? biasl : biasr;
    float* C = (y < 4) ? outL : outR;
    const int col0 = (y & 3) * 128;
    const int tid  = threadIdx.x;
    const int wave = tid >> 6;
    const int lane = tid & 63;
    const int str = tid >> 2;            // staging row (cc=0 half)
    const int skb = tid & 3;             // staging 16B chunk

    f32x4 acc[4][4];
#pragma unroll
    for (int i = 0; i < 4; ++i)
#pragma unroll
        for (int j = 0; j < 4; ++j) acc[i][j] = (f32x4){0.f, 0.f, 0.f, 0.f};

    const int abase = (wave & 1) * 2048;
    const int bbase = (wave >> 1) * 2048;
    const int rkb = lane >> 4;
    const int rrow = (lane & 15) ^ (rkb << 1);
    const int roff = rkb * 128 + rrow * 8;

    s8v pAh[2], pAl[2], pBh[2], pBl[2];
    const s8v zero8 = (s8v){0,0,0,0,0,0,0,0};

#define GLOAD(k0)                                                                     \
    {                                                                                 \
        _Pragma("unroll")                                                             \
        for (int cc = 0; cc < 2; ++cc) {                                              \
            int r = str + cc * 64;                                                    \
            if (row0 + r < M) {                                                       \
                pAh[cc] = *(const s8v*)(Ah + (size_t)(row0 + r) * 512 + (k0) + skb * 8); \
                pAl[cc] = *(const s8v*)(Al + (size_t)(row0 + r) * 512 + (k0) + skb * 8); \
            } else { pAh[cc] = zero8; pAl[cc] = zero8; }                              \
            pBh[cc] = *(const s8v*)(BTh + (size_t)(col0 + r) * 512 + (k0) + skb * 8); \
            pBl[cc] = *(const s8v*)(BTl + (size_t)(col0 + r) * 512 + (k0) + skb * 8); \
        }                                                                             \
    }

#define LSTORE(buf)                                                                   \
    {                                                                                 \
        _Pragma("unroll")                                                             \
        for (int cc = 0; cc < 2; ++cc) {                                              \
            int r = str + cc * 64;                                                    \
            int idx = (r >> 4) * 512 + skb * 128 + (((r & 15) ^ (skb << 1)) * 8);     \
            *(s8v*)&sAh[buf][idx] = pAh[cc];                                          \
            *(s8v*)&sAl[buf][idx] = pAl[cc];                                          \
            *(s8v*)&sBh[buf][idx] = pBh[cc];                                          \
            *(s8v*)&sBl[buf][idx] = pBl[cc];                                          \
        }                                                                             \
    }

    GLOAD(0);
    LSTORE(0);
    GLOAD(32);
    __syncthreads();

    for (int k0 = 0; k0 < 512; k0 += 32) {
        const int cur = (k0 >> 5) & 1;
#pragma unroll
        for (int sr = 0; sr < 4; ++sr) {
            s8v ah = *(const s8v*)&sAh[cur][abase + sr * 512 + roff];
            s8v al = *(const s8v*)&sAl[cur][abase + sr * 512 + roff];
#pragma unroll
            for (int sc = 0; sc < 4; ++sc) {
                s8v bh = *(const s8v*)&sBh[cur][bbase + sc * 512 + roff];
                s8v bl = *(const s8v*)&sBl[cur][bbase + sc * 512 + roff];
                acc[sr][sc] = __builtin_amdgcn_mfma_f32_16x16x32_bf16(ah, bh, acc[sr][sc], 0, 0, 0);
                acc[sr][sc] = __builtin_amdgcn_mfma_f32_16x16x32_bf16(al, bh, acc[sr][sc], 0, 0, 0);
                acc[sr][sc] = __builtin_amdgcn_mfma_f32_16x16x32_bf16(ah, bl, acc[sr][sc], 0, 0, 0);
            }
        }
        if (k0 + 32 < 512) {
            LSTORE(cur ^ 1);
            if (k0 + 64 < 512) GLOAD(k0 + 64);
            __syncthreads();
        }
    }
#undef GLOAD
#undef LSTORE
    // C/D frag layout (m89): col = lane&15, row = (lane>>4)*4 + j
    const int crow = row0 + (wave & 1) * 64;
    const int ccol = col0 + (wave >> 1) * 64;
#pragma unroll
    for (int sr = 0; sr < 4; ++sr) {
        int rbase = crow + sr * 16 + ((lane >> 4) << 2);
#pragma unroll
        for (int sc = 0; sc < 4; ++sc) {
            int col = ccol + sc * 16 + (lane & 15);
            float bb = bias[col];
#pragma unroll
            for (int j = 0; j < 4; ++j) {
                int r = rbase + j;
                if (r < M) C[(size_t)r * 512 + col] = acc[sr][sc][j] + bb;
            }
        }
    }
}

// ================= CSR build (once per launch; graph shared by both layers) =================

__global__ void hist_kernel(const int* __restrict__ edst, int* __restrict__ deg, int E, int Etot) {
    int e = blockIdx.x * blockDim.x + threadIdx.x;
    if (e >= Etot) return;
    int dst = (e < E) ? edst[e] : (e - E);
    atomicAdd(&deg[dst], 1);
}

__global__ __launch_bounds__(1024) void scan_kernel(const int* __restrict__ deg,
                                                    int* __restrict__ rowstart, int n) {
    __shared__ int buf[1024];
    __shared__ int carry;
    if (threadIdx.x == 0) carry = 0;
    __syncthreads();
    for (int base = 0; base < n; base += 1024) {
        int i = base + (int)threadIdx.x;
        int v = (i < n) ? deg[i] : 0;
        buf[threadIdx.x] = v;
        __syncthreads();
        for (int off = 1; off < 1024; off <<= 1) {
            int t = (threadIdx.x >= (unsigned)off) ? buf[threadIdx.x - off] : 0;
            __syncthreads();
            buf[threadIdx.x] += t;
            __syncthreads();
        }
        if (i < n) rowstart[i] = carry + buf[threadIdx.x] - v;
        int blocksum = buf[1023];
        __syncthreads();
        if (threadIdx.x == 0) carry += blocksum;
        __syncthreads();
    }
    if (threadIdx.x == 0) rowstart[n] = carry;
}

__global__ void scatter_kernel(const int* __restrict__ esrc, const int* __restrict__ edst,
                               const int* __restrict__ rowstart, int* __restrict__ cursor,
                               int* __restrict__ s_src, int E, int Etot) {
    int e = blockIdx.x * blockDim.x + threadIdx.x;
    if (e >= Etot) return;
    int src = (e < E) ? esrc[e] : (e - E);
    int dst = (e < E) ? edst[e] : (e - E);
    int pos = rowstart[dst] + atomicAdd(&cursor[dst], 1);
    s_src[pos] = src;
}

// ---- fused GATv2 edge phase: chunk-parallel online softmax (8 edges/iter) ----
// wave h = head h; lane owns 2 channels. Per chunk: 8 independent score chains
// (butterfly reduces interleave for ILP), ONE max-combine + rescale, then 8
// independent exp+fma accumulations. Exact block-online-softmax.
__global__ __launch_bounds__(256) void gat_fused_kernel(
        const float* __restrict__ xl, const float* __restrict__ xr,
        const float* __restrict__ att,
        const int* __restrict__ rowstart, const int* __restrict__ s_src,
        float* __restrict__ out) {
    int node = blockIdx.x;
    int h    = threadIdx.x >> 6;
    int lane = threadIdx.x & 63;
    int beg = rowstart[node];
    int end = rowstart[node + 1];
    int c0 = h * CCH + (lane << 1);
    float2 r2 = *(const float2*)(xr + (size_t)node * HCD + c0);
    float2 a2 = *(const float2*)(att + c0);
    float m = -3.0e38f, den = 0.f, acc0 = 0.f, acc1 = 0.f;

    for (int j = beg; j < end; j += 8) {
        int cnt = end - j;             // wave-uniform
        if (cnt > 8) cnt = 8;
        float2 xq[8];
        float s[8];
#pragma unroll
        for (int i = 0; i < 8; ++i)
            if (i < cnt)
                xq[i] = *(const float2*)(xl + (size_t)s_src[j + i] * HCD + c0);
#pragma unroll
        for (int i = 0; i < 8; ++i) {
            if (i < cnt) {
                float t0 = xq[i].x + r2.x; t0 = (t0 > 0.f) ? t0 : SLOPE * t0;
                float t1 = xq[i].y + r2.y; t1 = (t1 > 0.f) ? t1 : SLOPE * t1;
                s[i] = fmaf(t0, a2.x, t1 * a2.y);
            }
        }
        // 8 interleaved butterfly chains (independent -> ILP)
#pragma unroll
        for (int k = 1; k < 64; k <<= 1) {
#pragma unroll
            for (int i = 0; i < 8; ++i)
                if (i < cnt) s[i] += __shfl_xor(s[i], k);
        }
        float cm = -3.0e38f;
#pragma unroll
        for (int i = 0; i < 8; ++i)
            if (i < cnt) cm = fmaxf(cm, s[i]);
        float mn = fmaxf(m, cm);
        float rs = __expf(m - mn);     // 0 on first chunk, 1 when max unchanged
        den *= rs; acc0 *= rs; acc1 *= rs;
#pragma unroll
        for (int i = 0; i < 8; ++i) {
            if (i < cnt) {
                float p = __expf(s[i] - mn);
                den += p;
                acc0 = fmaf(p, xq[i].x, acc0);
                acc1 = fmaf(p, xq[i].y, acc1);
            }
        }
        m = mn;
    }
    float inv = 1.0f / (den + 1e-16f);
    *(float2*)(out + (size_t)node * HCD + c0) = make_float2(acc0 * inv, acc1 * inv);
}

// ---- BatchNorm statistics: per-channel sum and sum-of-squares ----
__global__ void bn_stats_kernel(const float* __restrict__ h, float* __restrict__ sum,
                                float* __restrict__ sumsq, int n) {
    int c = blockIdx.y * blockDim.x + threadIdx.x;   // 0..511
    int r0 = blockIdx.x * 128;
    int r1 = min(r0 + 128, n);
    float s = 0.f, s2 = 0.f;
    for (int r = r0; r < r1; ++r) {
        float v = h[(size_t)r * HCD + c];
        s += v;
        s2 = fmaf(v, v, s2);
    }
    atomicAdd(&sum[c], s);
    atomicAdd(&sumsq[c], s2);
}

__global__ void bn_finalize_kernel(const float* __restrict__ sum, const float* __restrict__ sumsq,
                                   const float* __restrict__ g, const float* __restrict__ b,
                                   float* __restrict__ scale, float* __restrict__ shift, int n) {
    int c = threadIdx.x;   // 512
    float inv_n = 1.0f / (float)n;
    float mu = sum[c] * inv_n;
    float var = fmaxf(sumsq[c] * inv_n - mu * mu, 0.0f);
    float sc = g[c] * rsqrtf(var + EPS_BN);
    scale[c] = sc;
    shift[c] = b[c] - mu * sc;
}

// ---- per-graph mean pool with fused BN+ReLU (batch is sorted) ----
__device__ __forceinline__ int lower_bound_i(const int* __restrict__ a, int n, int key) {
    int lo = 0, hi = n;
    while (lo < hi) {
        int mid = (lo + hi) >> 1;
        if (a[mid] < key) lo = mid + 1; else hi = mid;
    }
    return lo;
}

__global__ void pool_bnrelu_kernel(const float* __restrict__ h, const int* __restrict__ batch,
                                   const float* __restrict__ scale, const float* __restrict__ shift,
                                   float* __restrict__ pooled, int n) {
    int g = blockIdx.x;
    int c = threadIdx.x;   // 512
    int start = lower_bound_i(batch, n, g);
    int end   = lower_bound_i(batch, n, g + 1);
    float sc = scale[c], sh = shift[c];
    float s = 0.f;
    for (int r = start; r < end; ++r)
        s += fmaxf(fmaf(h[(size_t)r * HCD + c], sc, sh), 0.f);
    float cnt = (float)max(end - start, 1);
    pooled[(size_t)g * HCD + c] = s / cnt;
}

// ---- MLP head: relu([pooled|gfeat] @ fc1 + b1) @ fc2 + b2 ----
__global__ void head_kernel(const float* __restrict__ pooled, const float* __restrict__ gfeat,
                            const float* __restrict__ fc1w, const float* __restrict__ fc1b,
                            const float* __restrict__ fc2w, const float* __restrict__ fc2b,
                            float* __restrict__ out, int gdim) {
    int g = blockIdx.x;
    int j = threadIdx.x;   // 128
    float acc = fc1b[j];
    const float* prow = pooled + (size_t)g * HCD;
    for (int i = 0; i < HCD; ++i) acc = fmaf(prow[i], fc1w[i * CCH + j], acc);
    const float* grow = gfeat + (size_t)g * gdim;
    for (int i = 0; i < gdim; ++i) acc = fmaf(grow[i], fc1w[(HCD + i) * CCH + j], acc);
    acc = fmaxf(acc, 0.f);
    __shared__ float z[CCH];
    z[j] = acc * fc2w[j];
    __syncthreads();
    for (int s = CCH / 2; s > 0; s >>= 1) {
        if (j < s) z[j] += z[j + s];
        __syncthreads();
    }
    if (j == 0) out[g] = z[0] + fc2b[0];
}

extern "C" void kernel_launch(void* const* d_in, const int* in_sizes, int n_in,
                              void* d_out, int out_size, void* d_ws, size_t ws_size,
                              hipStream_t stream) {
    const float* x     = (const float*)d_in[0];
    const float* gfeat = (const float*)d_in[1];
    const float* W1l   = (const float*)d_in[2];
    const float* b1l   = (const float*)d_in[3];
    const float* W1r   = (const float*)d_in[4];
    const float* b1r   = (const float*)d_in[5];
    const float* att1  = (const float*)d_in[6];
    // d_in[7] = bias1: cancels through BN
    const float* W2l   = (const float*)d_in[8];
    const float* b2l   = (const float*)d_in[9];
    const float* W2r   = (const float*)d_in[10];
    const float* b2r   = (const float*)d_in[11];
    const float* att2  = (const float*)d_in[12];
    // d_in[13] = bias2: cancels through BN
    const float* bn1_g = (const float*)d_in[14];
    const float* bn1_b = (const float*)d_in[15];
    const float* bn2_g = (const float*)d_in[16];
    const float* bn2_b = (const float*)d_in[17];
    const float* fc1w  = (const float*)d_in[18];
    const float* fc1b  = (const float*)d_in[19];
    const float* fc2w  = (const float*)d_in[20];
    const float* fc2b  = (const float*)d_in[21];
    const int* eidx    = (const int*)d_in[22];
    const int* batch   = (const int*)d_in[23];

    const int n    = in_sizes[0] / 9;
    const int E    = in_sizes[22] / 2;
    const int Etot = E + n;
    const int b    = out_size;
    const int gdim = in_sizes[1] / b;
    const int* esrc = eidx;
    const int* edst = eidx + E;

    float* ws = (float*)d_ws;
    size_t nHC = (size_t)n * HCD;
    float* xl      = ws;
    float* xr      = xl + nHC;
    float* hbuf    = xr + nHC;
    int* deg       = (int*)(hbuf + nHC);     // n
    int* rowstart  = deg + n;                // n+1
    int* cursor    = rowstart + n + 1;       // n
    int* s_src     = cursor + n;             // Etot
    float* bnsum   = (float*)(s_src + Etot); // 512
    float* bnsumsq = bnsum + HCD;            // 512
    float* bnscale = bnsumsq + HCD;          // 512
    float* bnshift = bnscale + HCD;          // 512
    float* pooled  = bnshift + HCD;          // b*512
    unsigned short* Ah   = (unsigned short*)(pooled + (size_t)b * HCD);  // n*512 bf16
    unsigned short* Al   = Ah + nHC;
    unsigned short* BThl = Al + nHC;         // 512*512 each
    unsigned short* BTll = BThl + HCD * HCD;
    unsigned short* BThr = BTll + HCD * HCD;
    unsigned short* BTlr = BThr + HCD * HCD;

    const int BLK = 256;
    const int linBlocks  = (int)((nHC + BLK - 1) / BLK);
    const int eBlocks    = (Etot + BLK - 1) / BLK;
    const int bnxBlocks  = (n + 127) / 128;
    const int saBlocks   = (int)((nHC / 4 + BLK - 1) / BLK);
    const int nrt        = (n + 127) / 128;
    dim3 gemmGrid(nrt * 8);

    // ---------------- CSR build (shared by both layers) ----------------
    hipMemsetAsync(deg, 0, (size_t)(2 * n + 1) * sizeof(int), stream);
    hipMemsetAsync(cursor, 0, (size_t)n * sizeof(int), stream);
    hist_kernel<<<eBlocks, BLK, 0, stream>>>(edst, deg, E, Etot);
    scan_kernel<<<1, 1024, 0, stream>>>(deg, rowstart, n);
    scatter_kernel<<<eBlocks, BLK, 0, stream>>>(esrc, edst, rowstart, cursor, s_src, E, Etot);
    // weight split/transpose (graph-independent)
    splitBT_kernel<<<(HCD * HCD) / BLK, BLK, 0, stream>>>(W2l, W2r, BThl, BTll, BThr, BTlr);

    // ---------------- layer 1 ----------------
    lin1_kernel<<<linBlocks, BLK, 0, stream>>>(x, W1l, b1l, W1r, b1r, xl, xr, n);
    gat_fused_kernel<<<n, 256, 0, stream>>>(xl, xr, att1, rowstart, s_src, hbuf);
    hipMemsetAsync(bnsum, 0, HCD * 2 * sizeof(float), stream);
    bn_stats_kernel<<<dim3(bnxBlocks, 2), BLK, 0, stream>>>(hbuf, bnsum, bnsumsq, n);
    bn_finalize_kernel<<<1, HCD, 0, stream>>>(bnsum, bnsumsq, bn1_g, bn1_b, bnscale, bnshift, n);

    // ---------------- layer 2: BN1+ReLU fused into split; MFMA GEMM ----------------
    splitA_kernel<<<saBlocks, BLK, 0, stream>>>(hbuf, bnscale, bnshift, Ah, Al, (int)(nHC / 4));
    gemm_mfma_kernel<<<gemmGrid, BLK, 0, stream>>>(Ah, Al, BThl, BTll, BThr, BTlr,
                                                   b2l, b2r, xl, xr, n);
    gat_fused_kernel<<<n, 256, 0, stream>>>(xl, xr, att2, rowstart, s_src, hbuf);
    hipMemsetAsync(bnsum, 0, HCD * 2 * sizeof(float), stream);
    bn_stats_kernel<<<dim3(bnxBlocks, 2), BLK, 0, stream>>>(hbuf, bnsum, bnsumsq, n);
    bn_finalize_kernel<<<1, HCD, 0, stream>>>(bnsum, bnsumsq, bn2_g, bn2_b, bnscale, bnshift, n);

    // ---------------- readout (BN2+ReLU fused into pool) ----------------
    pool_bnrelu_kernel<<<b, HCD, 0, stream>>>(hbuf, batch, bnscale, bnshift, pooled, n);
    head_kernel<<<b, CCH, 0, stream>>>(pooled, gfeat, fc1w, fc1b, fc2w, fc2b, (float*)d_out, gdim);
}

// Round 16
// 775.765 us; speedup vs baseline: 1.2137x; 1.2137x over previous
//
#include <hip/hip_runtime.h>
#include <math.h>

#define NHEAD 4
#define CCH 128
#define HCD 512
#define SLOPE 0.2f
#define EPS_BN 1e-5f
#define PSPLIT 8

typedef short s8v __attribute__((ext_vector_type(8)));
typedef float f32x4 __attribute__((ext_vector_type(4)));

// RNE f32 -> bf16 (finite values), and back
__device__ __forceinline__ unsigned short f2bf(float f) {
    unsigned int u = __float_as_uint(f);
    return (unsigned short)((u + 0x7FFFu + ((u >> 16) & 1u)) >> 16);
}
__device__ __forceinline__ float bf2f(unsigned short b) {
    return __uint_as_float(((unsigned int)b) << 16);
}

// ---- layer 1 node transforms: x[N,9] @ W[9,512] + b, both l and r ----
__global__ void lin1_kernel(const float* __restrict__ x,
                            const float* __restrict__ Wl, const float* __restrict__ bl,
                            const float* __restrict__ Wr, const float* __restrict__ br,
                            float* __restrict__ xl, float* __restrict__ xr, int n) {
    int gid = blockIdx.x * blockDim.x + threadIdx.x;
    if (gid >= n * HCD) return;
    int node = gid >> 9;
    int c = gid & (HCD - 1);
    const float* xrow = x + node * 9;
    float a = bl[c], bz = br[c];
#pragma unroll
    for (int k = 0; k < 9; ++k) {
        float xv = xrow[k];
        a  = fmaf(xv, Wl[k * HCD + c], a);
        bz = fmaf(xv, Wr[k * HCD + c], bz);
    }
    xl[gid] = a;
    xr[gid] = bz;
}

// ---- split A = relu(bn(h)) into bf16 hi/lo, row-major [n][512] ----
__global__ void splitA_kernel(const float* __restrict__ h,
                              const float* __restrict__ scale, const float* __restrict__ shift,
                              unsigned short* __restrict__ Ah, unsigned short* __restrict__ Al,
                              int total4) {
    int gid = blockIdx.x * blockDim.x + threadIdx.x;
    if (gid >= total4) return;
    int c4 = gid & 127;
    float4 v = ((const float4*)h)[gid];
    float4 sc = ((const float4*)scale)[c4];
    float4 sh = ((const float4*)shift)[c4];
    float f0 = fmaxf(fmaf(v.x, sc.x, sh.x), 0.f);
    float f1 = fmaxf(fmaf(v.y, sc.y, sh.y), 0.f);
    float f2 = fmaxf(fmaf(v.z, sc.z, sh.z), 0.f);
    float f3 = fmaxf(fmaf(v.w, sc.w, sh.w), 0.f);
    unsigned short h0 = f2bf(f0), h1 = f2bf(f1), h2 = f2bf(f2), h3 = f2bf(f3);
    short4 hv = make_short4((short)h0, (short)h1, (short)h2, (short)h3);
    short4 lv = make_short4((short)f2bf(f0 - bf2f(h0)), (short)f2bf(f1 - bf2f(h1)),
                            (short)f2bf(f2 - bf2f(h2)), (short)f2bf(f3 - bf2f(h3)));
    ((short4*)Ah)[gid] = hv;
    ((short4*)Al)[gid] = lv;
}

// ---- split + transpose W[k][col] -> BT[col][k] bf16 hi/lo, both matrices ----
__global__ void splitBT_kernel(const float* __restrict__ Wl, const float* __restrict__ Wr,
                               unsigned short* __restrict__ BThl, unsigned short* __restrict__ BTll,
                               unsigned short* __restrict__ BThr, unsigned short* __restrict__ BTlr) {
    int gid = blockIdx.x * blockDim.x + threadIdx.x;   // 512*512
    int col = gid >> 9;
    int k = gid & 511;
    float vl = Wl[k * HCD + col];
    float vr = Wr[k * HCD + col];
    unsigned short hl = f2bf(vl);
    unsigned short hr = f2bf(vr);
    BThl[gid] = hl; BTll[gid] = f2bf(vl - bf2f(hl));
    BThr[gid] = hr; BTlr[gid] = f2bf(vr - bf2f(hr));
}

// ---- split-bf16 MFMA GEMM, LDS double-buffered (1 barrier/k-step), XCD-swizzled ----
__global__ __launch_bounds__(256) void gemm_mfma_kernel(
        const unsigned short* __restrict__ Ah, const unsigned short* __restrict__ Al,
        const unsigned short* __restrict__ BThL, const unsigned short* __restrict__ BTlL,
        const unsigned short* __restrict__ BThR, const unsigned short* __restrict__ BTlR,
        const float* __restrict__ biasl, const float* __restrict__ biasr,
        float* __restrict__ outL, float* __restrict__ outR, int M) {
    __shared__ short sAh[2][4096], sAl[2][4096], sBh[2][4096], sBl[2][4096];  // 64 KB
    const int nrt = gridDim.x >> 3;
    const int bphys = blockIdx.x;
    const int l = (bphys & 7) * nrt + (bphys >> 3);
    const int y = l & 7;
    const int row0 = (l >> 3) * 128;
    const unsigned short* BTh = (y < 4) ? BThL : BThR;
    const unsigned short* BTl = (y < 4) ? BTlL : BTlR;
    const float* bias = (y < 4) ? biasl : biasr;
    float* C = (y < 4) ? outL : outR;
    const int col0 = (y & 3) * 128;
    const int tid  = threadIdx.x;
    const int wave = tid >> 6;
    const int lane = tid & 63;
    const int str = tid >> 2;            // staging row (cc=0 half)
    const int skb = tid & 3;             // staging 16B chunk

    f32x4 acc[4][4];
#pragma unroll
    for (int i = 0; i < 4; ++i)
#pragma unroll
        for (int j = 0; j < 4; ++j) acc[i][j] = (f32x4){0.f, 0.f, 0.f, 0.f};

    const int abase = (wave & 1) * 2048;
    const int bbase = (wave >> 1) * 2048;
    const int rkb = lane >> 4;
    const int rrow = (lane & 15) ^ (rkb << 1);
    const int roff = rkb * 128 + rrow * 8;

    s8v pAh[2], pAl[2], pBh[2], pBl[2];
    const s8v zero8 = (s8v){0,0,0,0,0,0,0,0};

#define GLOAD(k0)                                                                     \
    {                                                                                 \
        _Pragma("unroll")                                                             \
        for (int cc = 0; cc < 2; ++cc) {                                              \
            int r = str + cc * 64;                                                    \
            if (row0 + r < M) {                                                       \
                pAh[cc] = *(const s8v*)(Ah + (size_t)(row0 + r) * 512 + (k0) + skb * 8); \
                pAl[cc] = *(const s8v*)(Al + (size_t)(row0 + r) * 512 + (k0) + skb * 8); \
            } else { pAh[cc] = zero8; pAl[cc] = zero8; }                              \
            pBh[cc] = *(const s8v*)(BTh + (size_t)(col0 + r) * 512 + (k0) + skb * 8); \
            pBl[cc] = *(const s8v*)(BTl + (size_t)(col0 + r) * 512 + (k0) + skb * 8); \
        }                                                                             \
    }

#define LSTORE(buf)                                                                   \
    {                                                                                 \
        _Pragma("unroll")                                                             \
        for (int cc = 0; cc < 2; ++cc) {                                              \
            int r = str + cc * 64;                                                    \
            int idx = (r >> 4) * 512 + skb * 128 + (((r & 15) ^ (skb << 1)) * 8);     \
            *(s8v*)&sAh[buf][idx] = pAh[cc];                                          \
            *(s8v*)&sAl[buf][idx] = pAl[cc];                                          \
            *(s8v*)&sBh[buf][idx] = pBh[cc];                                          \
            *(s8v*)&sBl[buf][idx] = pBl[cc];                                          \
        }                                                                             \
    }

    GLOAD(0);
    LSTORE(0);
    GLOAD(32);
    __syncthreads();

    for (int k0 = 0; k0 < 512; k0 += 32) {
        const int cur = (k0 >> 5) & 1;
#pragma unroll
        for (int sr = 0; sr < 4; ++sr) {
            s8v ah = *(const s8v*)&sAh[cur][abase + sr * 512 + roff];
            s8v al = *(const s8v*)&sAl[cur][abase + sr * 512 + roff];
#pragma unroll
            for (int sc = 0; sc < 4; ++sc) {
                s8v bh = *(const s8v*)&sBh[cur][bbase + sc * 512 + roff];
                s8v bl = *(const s8v*)&sBl[cur][bbase + sc * 512 + roff];
                acc[sr][sc] = __builtin_amdgcn_mfma_f32_16x16x32_bf16(ah, bh, acc[sr][sc], 0, 0, 0);
                acc[sr][sc] = __builtin_amdgcn_mfma_f32_16x16x32_bf16(al, bh, acc[sr][sc], 0, 0, 0);
                acc[sr][sc] = __builtin_amdgcn_mfma_f32_16x16x32_bf16(ah, bl, acc[sr][sc], 0, 0, 0);
            }
        }
        if (k0 + 32 < 512) {
            LSTORE(cur ^ 1);
            if (k0 + 64 < 512) GLOAD(k0 + 64);
            __syncthreads();
        }
    }
#undef GLOAD
#undef LSTORE
    // C/D frag layout (m89): col = lane&15, row = (lane>>4)*4 + j
    const int crow = row0 + (wave & 1) * 64;
    const int ccol = col0 + (wave >> 1) * 64;
#pragma unroll
    for (int sr = 0; sr < 4; ++sr) {
        int rbase = crow + sr * 16 + ((lane >> 4) << 2);
#pragma unroll
        for (int sc = 0; sc < 4; ++sc) {
            int col = ccol + sc * 16 + (lane & 15);
            float bb = bias[col];
#pragma unroll
            for (int j = 0; j < 4; ++j) {
                int r = rbase + j;
                if (r < M) C[(size_t)r * 512 + col] = acc[sr][sc][j] + bb;
            }
        }
    }
}

// ================= CSR build (once per launch; graph shared by both layers) =================

__global__ void hist_kernel(const int* __restrict__ edst, int* __restrict__ deg, int E, int Etot) {
    int e = blockIdx.x * blockDim.x + threadIdx.x;
    if (e >= Etot) return;
    int dst = (e < E) ? edst[e] : (e - E);
    atomicAdd(&deg[dst], 1);
}

__global__ __launch_bounds__(1024) void scan_kernel(const int* __restrict__ deg,
                                                    int* __restrict__ rowstart, int n) {
    __shared__ int buf[1024];
    __shared__ int carry;
    if (threadIdx.x == 0) carry = 0;
    __syncthreads();
    for (int base = 0; base < n; base += 1024) {
        int i = base + (int)threadIdx.x;
        int v = (i < n) ? deg[i] : 0;
        buf[threadIdx.x] = v;
        __syncthreads();
        for (int off = 1; off < 1024; off <<= 1) {
            int t = (threadIdx.x >= (unsigned)off) ? buf[threadIdx.x - off] : 0;
            __syncthreads();
            buf[threadIdx.x] += t;
            __syncthreads();
        }
        if (i < n) rowstart[i] = carry + buf[threadIdx.x] - v;
        int blocksum = buf[1023];
        __syncthreads();
        if (threadIdx.x == 0) carry += blocksum;
        __syncthreads();
    }
    if (threadIdx.x == 0) rowstart[n] = carry;
}

__global__ void scatter_kernel(const int* __restrict__ esrc, const int* __restrict__ edst,
                               const int* __restrict__ rowstart, int* __restrict__ cursor,
                               int* __restrict__ s_src, int E, int Etot) {
    int e = blockIdx.x * blockDim.x + threadIdx.x;
    if (e >= Etot) return;
    int src = (e < E) ? esrc[e] : (e - E);
    int dst = (e < E) ? edst[e] : (e - E);
    int pos = rowstart[dst] + atomicAdd(&cursor[dst], 1);
    s_src[pos] = src;
}

// ---- fully fused GATv2 edge phase: 2-edge-pair online softmax, 4-deep gather pipeline ----
__global__ __launch_bounds__(256) void gat_fused_kernel(
        const float* __restrict__ xl, const float* __restrict__ xr,
        const float* __restrict__ att,
        const int* __restrict__ rowstart, const int* __restrict__ s_src,
        float* __restrict__ out) {
    int node = blockIdx.x;
    int h    = threadIdx.x >> 6;
    int lane = threadIdx.x & 63;
    int beg = rowstart[node];
    int end = rowstart[node + 1];
    int c0 = h * CCH + (lane << 1);
    float2 r2 = *(const float2*)(xr + (size_t)node * HCD + c0);
    float2 a2 = *(const float2*)(att + c0);
    float m = -3.0e38f, den = 0.f, acc0 = 0.f, acc1 = 0.f;

    int j = beg;
    float2 q0, q1, q2, q3;
    q0 = *(const float2*)(xl + (size_t)s_src[j] * HCD + c0);   // deg >= 1 (self-loop)
    if (j + 1 < end) q1 = *(const float2*)(xl + (size_t)s_src[j + 1] * HCD + c0);
    if (j + 2 < end) q2 = *(const float2*)(xl + (size_t)s_src[j + 2] * HCD + c0);
    if (j + 3 < end) q3 = *(const float2*)(xl + (size_t)s_src[j + 3] * HCD + c0);

    while (j + 1 < end) {
        float2 A = q0, B = q1;
        q0 = q2; q1 = q3;
        if (j + 4 < end) q2 = *(const float2*)(xl + (size_t)s_src[j + 4] * HCD + c0);
        if (j + 5 < end) q3 = *(const float2*)(xl + (size_t)s_src[j + 5] * HCD + c0);
        float ta0 = A.x + r2.x; ta0 = (ta0 > 0.f) ? ta0 : SLOPE * ta0;
        float ta1 = A.y + r2.y; ta1 = (ta1 > 0.f) ? ta1 : SLOPE * ta1;
        float tb0 = B.x + r2.x; tb0 = (tb0 > 0.f) ? tb0 : SLOPE * tb0;
        float tb1 = B.y + r2.y; tb1 = (tb1 > 0.f) ? tb1 : SLOPE * tb1;
        float sA = fmaf(ta0, a2.x, ta1 * a2.y);
        float sB = fmaf(tb0, a2.x, tb1 * a2.y);
#pragma unroll
        for (int k = 1; k < 64; k <<= 1) {
            sA += __shfl_xor(sA, k);
            sB += __shfl_xor(sB, k);
        }
        float mn = fmaxf(m, fmaxf(sA, sB));
        float sc = expf(m - mn);
        float pA = expf(sA - mn);
        float pB = expf(sB - mn);
        den  = fmaf(den,  sc, pA + pB);
        acc0 = fmaf(acc0, sc, fmaf(pA, A.x, pB * B.x));
        acc1 = fmaf(acc1, sc, fmaf(pA, A.y, pB * B.y));
        m = mn;
        j += 2;
    }
    if (j < end) {   // odd tail
        float2 A = q0;
        float ta0 = A.x + r2.x; ta0 = (ta0 > 0.f) ? ta0 : SLOPE * ta0;
        float ta1 = A.y + r2.y; ta1 = (ta1 > 0.f) ? ta1 : SLOPE * ta1;
        float sA = fmaf(ta0, a2.x, ta1 * a2.y);
#pragma unroll
        for (int k = 1; k < 64; k <<= 1) sA += __shfl_xor(sA, k);
        float mn = fmaxf(m, sA);
        float sc = expf(m - mn);
        float pA = expf(sA - mn);
        den  = fmaf(den,  sc, pA);
        acc0 = fmaf(acc0, sc, pA * A.x);
        acc1 = fmaf(acc1, sc, pA * A.y);
    }
    float inv = 1.0f / (den + 1e-16f);
    *(float2*)(out + (size_t)node * HCD + c0) = make_float2(acc0 * inv, acc1 * inv);
}

// ---- BatchNorm statistics: per-channel sum and sum-of-squares ----
__global__ void bn_stats_kernel(const float* __restrict__ h, float* __restrict__ sum,
                                float* __restrict__ sumsq, int n) {
    int c = blockIdx.y * blockDim.x + threadIdx.x;   // 0..511
    int r0 = blockIdx.x * 128;
    int r1 = min(r0 + 128, n);
    float s = 0.f, s2 = 0.f;
    for (int r = r0; r < r1; ++r) {
        float v = h[(size_t)r * HCD + c];
        s += v;
        s2 = fmaf(v, v, s2);
    }
    atomicAdd(&sum[c], s);
    atomicAdd(&sumsq[c], s2);
}

__global__ void bn_finalize_kernel(const float* __restrict__ sum, const float* __restrict__ sumsq,
                                   const float* __restrict__ g, const float* __restrict__ b,
                                   float* __restrict__ scale, float* __restrict__ shift, int n) {
    int c = threadIdx.x;   // 512
    float inv_n = 1.0f / (float)n;
    float mu = sum[c] * inv_n;
    float var = fmaxf(sumsq[c] * inv_n - mu * mu, 0.0f);
    float sc = g[c] * rsqrtf(var + EPS_BN);
    scale[c] = sc;
    shift[c] = b[c] - mu * sc;
}

// ---- per-graph mean pool, row-chunk parallel (batch is sorted) ----
__device__ __forceinline__ int lower_bound_i(const int* __restrict__ a, int n, int key) {
    int lo = 0, hi = n;
    while (lo < hi) {
        int mid = (lo + hi) >> 1;
        if (a[mid] < key) lo = mid + 1; else hi = mid;
    }
    return lo;
}

// grid (b, PSPLIT): partial BN2+ReLU sums atomically accumulated into pooled (pre-zeroed)
__global__ void pool_partial_kernel(const float* __restrict__ h, const int* __restrict__ batch,
                                    const float* __restrict__ scale, const float* __restrict__ shift,
                                    float* __restrict__ pooled, int n) {
    int g = blockIdx.x;
    int chunk = blockIdx.y;
    int c = threadIdx.x;   // 512
    int start = lower_bound_i(batch, n, g);
    int end   = lower_bound_i(batch, n, g + 1);
    int len = end - start;
    int cs = start + (int)(((long long)len * chunk) / PSPLIT);
    int ce = start + (int)(((long long)len * (chunk + 1)) / PSPLIT);
    if (cs >= ce) return;
    float sc = scale[c], sh = shift[c];
    float s = 0.f;
    for (int r = cs; r < ce; ++r)
        s += fmaxf(fmaf(h[(size_t)r * HCD + c], sc, sh), 0.f);
    atomicAdd(&pooled[(size_t)g * HCD + c], s);
}

// ---- MLP head: relu([pooled_sum/cnt | gfeat] @ fc1 + b1) @ fc2 + b2 ----
__global__ void head_kernel(const float* __restrict__ pooled, const float* __restrict__ gfeat,
                            const int* __restrict__ batch,
                            const float* __restrict__ fc1w, const float* __restrict__ fc1b,
                            const float* __restrict__ fc2w, const float* __restrict__ fc2b,
                            float* __restrict__ out, int gdim, int n) {
    int g = blockIdx.x;
    int j = threadIdx.x;   // 128
    int start = lower_bound_i(batch, n, g);
    int end   = lower_bound_i(batch, n, g + 1);
    float icnt = 1.0f / (float)max(end - start, 1);
    float acc = fc1b[j];
    const float* prow = pooled + (size_t)g * HCD;
    for (int i = 0; i < HCD; ++i) acc = fmaf(prow[i] * icnt, fc1w[i * CCH + j], acc);
    const float* grow = gfeat + (size_t)g * gdim;
    for (int i = 0; i < gdim; ++i) acc = fmaf(grow[i], fc1w[(HCD + i) * CCH + j], acc);
    acc = fmaxf(acc, 0.f);
    __shared__ float z[CCH];
    z[j] = acc * fc2w[j];
    __syncthreads();
    for (int s = CCH / 2; s > 0; s >>= 1) {
        if (j < s) z[j] += z[j + s];
        __syncthreads();
    }
    if (j == 0) out[g] = z[0] + fc2b[0];
}

extern "C" void kernel_launch(void* const* d_in, const int* in_sizes, int n_in,
                              void* d_out, int out_size, void* d_ws, size_t ws_size,
                              hipStream_t stream) {
    const float* x     = (const float*)d_in[0];
    const float* gfeat = (const float*)d_in[1];
    const float* W1l   = (const float*)d_in[2];
    const float* b1l   = (const float*)d_in[3];
    const float* W1r   = (const float*)d_in[4];
    const float* b1r   = (const float*)d_in[5];
    const float* att1  = (const float*)d_in[6];
    // d_in[7] = bias1: cancels through BN
    const float* W2l   = (const float*)d_in[8];
    const float* b2l   = (const float*)d_in[9];
    const float* W2r   = (const float*)d_in[10];
    const float* b2r   = (const float*)d_in[11];
    const float* att2  = (const float*)d_in[12];
    // d_in[13] = bias2: cancels through BN
    const float* bn1_g = (const float*)d_in[14];
    const float* bn1_b = (const float*)d_in[15];
    const float* bn2_g = (const float*)d_in[16];
    const float* bn2_b = (const float*)d_in[17];
    const float* fc1w  = (const float*)d_in[18];
    const float* fc1b  = (const float*)d_in[19];
    const float* fc2w  = (const float*)d_in[20];
    const float* fc2b  = (const float*)d_in[21];
    const int* eidx    = (const int*)d_in[22];
    const int* batch   = (const int*)d_in[23];

    const int n    = in_sizes[0] / 9;
    const int E    = in_sizes[22] / 2;
    const int Etot = E + n;
    const int b    = out_size;
    const int gdim = in_sizes[1] / b;
    const int* esrc = eidx;
    const int* edst = eidx + E;

    float* ws = (float*)d_ws;
    size_t nHC = (size_t)n * HCD;
    float* xl      = ws;
    float* xr      = xl + nHC;
    float* hbuf    = xr + nHC;
    int* deg       = (int*)(hbuf + nHC);     // n
    int* rowstart  = deg + n;                // n+1
    int* cursor    = rowstart + n + 1;       // n
    int* s_src     = cursor + n;             // Etot
    float* bnsum   = (float*)(s_src + Etot); // 512
    float* bnsumsq = bnsum + HCD;            // 512
    float* bnscale = bnsumsq + HCD;          // 512
    float* bnshift = bnscale + HCD;          // 512
    float* pooled  = bnshift + HCD;          // b*512
    unsigned short* Ah   = (unsigned short*)(pooled + (size_t)b * HCD);  // n*512 bf16
    unsigned short* Al   = Ah + nHC;
    unsigned short* BThl = Al + nHC;         // 512*512 each
    unsigned short* BTll = BThl + HCD * HCD;
    unsigned short* BThr = BTll + HCD * HCD;
    unsigned short* BTlr = BThr + HCD * HCD;

    const int BLK = 256;
    const int linBlocks  = (int)((nHC + BLK - 1) / BLK);
    const int eBlocks    = (Etot + BLK - 1) / BLK;
    const int bnxBlocks  = (n + 127) / 128;
    const int saBlocks   = (int)((nHC / 4 + BLK - 1) / BLK);
    const int nrt        = (n + 127) / 128;
    dim3 gemmGrid(nrt * 8);

    // ---------------- CSR build (shared by both layers) ----------------
    hipMemsetAsync(deg, 0, (size_t)(2 * n + 1) * sizeof(int), stream);
    hipMemsetAsync(cursor, 0, (size_t)n * sizeof(int), stream);
    hist_kernel<<<eBlocks, BLK, 0, stream>>>(edst, deg, E, Etot);
    scan_kernel<<<1, 1024, 0, stream>>>(deg, rowstart, n);
    scatter_kernel<<<eBlocks, BLK, 0, stream>>>(esrc, edst, rowstart, cursor, s_src, E, Etot);
    // weight split/transpose (graph-independent)
    splitBT_kernel<<<(HCD * HCD) / BLK, BLK, 0, stream>>>(W2l, W2r, BThl, BTll, BThr, BTlr);

    // ---------------- layer 1 ----------------
    lin1_kernel<<<linBlocks, BLK, 0, stream>>>(x, W1l, b1l, W1r, b1r, xl, xr, n);
    gat_fused_kernel<<<n, 256, 0, stream>>>(xl, xr, att1, rowstart, s_src, hbuf);
    hipMemsetAsync(bnsum, 0, HCD * 2 * sizeof(float), stream);
    bn_stats_kernel<<<dim3(bnxBlocks, 2), BLK, 0, stream>>>(hbuf, bnsum, bnsumsq, n);
    bn_finalize_kernel<<<1, HCD, 0, stream>>>(bnsum, bnsumsq, bn1_g, bn1_b, bnscale, bnshift, n);

    // ---------------- layer 2: BN1+ReLU fused into split; MFMA GEMM ----------------
    splitA_kernel<<<saBlocks, BLK, 0, stream>>>(hbuf, bnscale, bnshift, Ah, Al, (int)(nHC / 4));
    gemm_mfma_kernel<<<gemmGrid, BLK, 0, stream>>>(Ah, Al, BThl, BTll, BThr, BTlr,
                                                   b2l, b2r, xl, xr, n);
    gat_fused_kernel<<<n, 256, 0, stream>>>(xl, xr, att2, rowstart, s_src, hbuf);
    hipMemsetAsync(bnsum, 0, HCD * 2 * sizeof(float), stream);
    bn_stats_kernel<<<dim3(bnxBlocks, 2), BLK, 0, stream>>>(hbuf, bnsum, bnsumsq, n);
    bn_finalize_kernel<<<1, HCD, 0, stream>>>(bnsum, bnsumsq, bn2_g, bn2_b, bnscale, bnshift, n);

    // ---------------- readout (BN2+ReLU fused into chunked pool) ----------------
    hipMemsetAsync(pooled, 0, (size_t)b * HCD * sizeof(float), stream);
    pool_partial_kernel<<<dim3(b, PSPLIT), HCD, 0, stream>>>(hbuf, batch, bnscale, bnshift, pooled, n);
    head_kernel<<<b, CCH, 0, stream>>>(pooled, gfeat, batch, fc1w, fc1b, fc2w, fc2b,
                                       (float*)d_out, gdim, n);
}

// Round 17
// 713.538 us; speedup vs baseline: 1.3195x; 1.0872x over previous
//
#include <hip/hip_runtime.h>
#include <math.h>

#define NHEAD 4
#define CCH 128
#define HCD 512
#define SLOPE 0.2f
#define EPS_BN 1e-5f
#define PSPLIT 8

typedef short s8v __attribute__((ext_vector_type(8)));
typedef float f32x4 __attribute__((ext_vector_type(4)));

// RNE f32 -> bf16 (finite values), and back
__device__ __forceinline__ unsigned short f2bf(float f) {
    unsigned int u = __float_as_uint(f);
    return (unsigned short)((u + 0x7FFFu + ((u >> 16) & 1u)) >> 16);
}
__device__ __forceinline__ float bf2f(unsigned short b) {
    return __uint_as_float(((unsigned int)b) << 16);
}

// ---- layer 1 node transforms: x[N,9] @ W[9,512] + b, both l and r ----
__global__ void lin1_kernel(const float* __restrict__ x,
                            const float* __restrict__ Wl, const float* __restrict__ bl,
                            const float* __restrict__ Wr, const float* __restrict__ br,
                            float* __restrict__ xl, float* __restrict__ xr, int n) {
    int gid = blockIdx.x * blockDim.x + threadIdx.x;
    if (gid >= n * HCD) return;
    int node = gid >> 9;
    int c = gid & (HCD - 1);
    const float* xrow = x + node * 9;
    float a = bl[c], bz = br[c];
#pragma unroll
    for (int k = 0; k < 9; ++k) {
        float xv = xrow[k];
        a  = fmaf(xv, Wl[k * HCD + c], a);
        bz = fmaf(xv, Wr[k * HCD + c], bz);
    }
    xl[gid] = a;
    xr[gid] = bz;
}

// ---- split A = relu(bn(h)) into bf16 hi/lo, row-major [n][512] ----
__global__ void splitA_kernel(const float* __restrict__ h,
                              const float* __restrict__ scale, const float* __restrict__ shift,
                              unsigned short* __restrict__ Ah, unsigned short* __restrict__ Al,
                              int total4) {
    int gid = blockIdx.x * blockDim.x + threadIdx.x;
    if (gid >= total4) return;
    int c4 = gid & 127;
    float4 v = ((const float4*)h)[gid];
    float4 sc = ((const float4*)scale)[c4];
    float4 sh = ((const float4*)shift)[c4];
    float f0 = fmaxf(fmaf(v.x, sc.x, sh.x), 0.f);
    float f1 = fmaxf(fmaf(v.y, sc.y, sh.y), 0.f);
    float f2 = fmaxf(fmaf(v.z, sc.z, sh.z), 0.f);
    float f3 = fmaxf(fmaf(v.w, sc.w, sh.w), 0.f);
    unsigned short h0 = f2bf(f0), h1 = f2bf(f1), h2 = f2bf(f2), h3 = f2bf(f3);
    short4 hv = make_short4((short)h0, (short)h1, (short)h2, (short)h3);
    short4 lv = make_short4((short)f2bf(f0 - bf2f(h0)), (short)f2bf(f1 - bf2f(h1)),
                            (short)f2bf(f2 - bf2f(h2)), (short)f2bf(f3 - bf2f(h3)));
    ((short4*)Ah)[gid] = hv;
    ((short4*)Al)[gid] = lv;
}

// ---- split + transpose W[k][col] -> BT[col][k] bf16 hi/lo, both matrices ----
__global__ void splitBT_kernel(const float* __restrict__ Wl, const float* __restrict__ Wr,
                               unsigned short* __restrict__ BThl, unsigned short* __restrict__ BTll,
                               unsigned short* __restrict__ BThr, unsigned short* __restrict__ BTlr) {
    int gid = blockIdx.x * blockDim.x + threadIdx.x;   // 512*512
    int col = gid >> 9;
    int k = gid & 511;
    float vl = Wl[k * HCD + col];
    float vr = Wr[k * HCD + col];
    unsigned short hl = f2bf(vl);
    unsigned short hr = f2bf(vr);
    BThl[gid] = hl; BTll[gid] = f2bf(vl - bf2f(hl));
    BThr[gid] = hr; BTlr[gid] = f2bf(vr - bf2f(hr));
}

// ---- split-bf16 MFMA GEMM, LDS double-buffered (1 barrier/k-step), XCD-swizzled ----
__global__ __launch_bounds__(256) void gemm_mfma_kernel(
        const unsigned short* __restrict__ Ah, const unsigned short* __restrict__ Al,
        const unsigned short* __restrict__ BThL, const unsigned short* __restrict__ BTlL,
        const unsigned short* __restrict__ BThR, const unsigned short* __restrict__ BTlR,
        const float* __restrict__ biasl, const float* __restrict__ biasr,
        float* __restrict__ outL, float* __restrict__ outR, int M) {
    __shared__ short sAh[2][4096], sAl[2][4096], sBh[2][4096], sBl[2][4096];  // 64 KB
    const int nrt = gridDim.x >> 3;
    const int bphys = blockIdx.x;
    const int l = (bphys & 7) * nrt + (bphys >> 3);
    const int y = l & 7;
    const int row0 = (l >> 3) * 128;
    const unsigned short* BTh = (y < 4) ? BThL : BThR;
    const unsigned short* BTl = (y < 4) ? BTlL : BTlR;
    const float* bias = (y < 4) ? biasl : biasr;
    float* C = (y < 4) ? outL : outR;
    const int col0 = (y & 3) * 128;
    const int tid  = threadIdx.x;
    const int wave = tid >> 6;
    const int lane = tid & 63;
    const int str = tid >> 2;            // staging row (cc=0 half)
    const int skb = tid & 3;             // staging 16B chunk

    f32x4 acc[4][4];
#pragma unroll
    for (int i = 0; i < 4; ++i)
#pragma unroll
        for (int j = 0; j < 4; ++j) acc[i][j] = (f32x4){0.f, 0.f, 0.f, 0.f};

    const int abase = (wave & 1) * 2048;
    const int bbase = (wave >> 1) * 2048;
    const int rkb = lane >> 4;
    const int rrow = (lane & 15) ^ (rkb << 1);
    const int roff = rkb * 128 + rrow * 8;

    s8v pAh[2], pAl[2], pBh[2], pBl[2];
    const s8v zero8 = (s8v){0,0,0,0,0,0,0,0};

#define GLOAD(k0)                                                                     \
    {                                                                                 \
        _Pragma("unroll")                                                             \
        for (int cc = 0; cc < 2; ++cc) {                                              \
            int r = str + cc * 64;                                                    \
            if (row0 + r < M) {                                                       \
                pAh[cc] = *(const s8v*)(Ah + (size_t)(row0 + r) * 512 + (k0) + skb * 8); \
                pAl[cc] = *(const s8v*)(Al + (size_t)(row0 + r) * 512 + (k0) + skb * 8); \
            } else { pAh[cc] = zero8; pAl[cc] = zero8; }                              \
            pBh[cc] = *(const s8v*)(BTh + (size_t)(col0 + r) * 512 + (k0) + skb * 8); \
            pBl[cc] = *(const s8v*)(BTl + (size_t)(col0 + r) * 512 + (k0) + skb * 8); \
        }                                                                             \
    }

#define LSTORE(buf)                                                                   \
    {                                                                                 \
        _Pragma("unroll")                                                             \
        for (int cc = 0; cc < 2; ++cc) {                                              \
            int r = str + cc * 64;                                                    \
            int idx = (r >> 4) * 512 + skb * 128 + (((r & 15) ^ (skb << 1)) * 8);     \
            *(s8v*)&sAh[buf][idx] = pAh[cc];                                          \
            *(s8v*)&sAl[buf][idx] = pAl[cc];                                          \
            *(s8v*)&sBh[buf][idx] = pBh[cc];                                          \
            *(s8v*)&sBl[buf][idx] = pBl[cc];                                          \
        }                                                                             \
    }

    GLOAD(0);
    LSTORE(0);
    GLOAD(32);
    __syncthreads();

    for (int k0 = 0; k0 < 512; k0 += 32) {
        const int cur = (k0 >> 5) & 1;
#pragma unroll
        for (int sr = 0; sr < 4; ++sr) {
            s8v ah = *(const s8v*)&sAh[cur][abase + sr * 512 + roff];
            s8v al = *(const s8v*)&sAl[cur][abase + sr * 512 + roff];
#pragma unroll
            for (int sc = 0; sc < 4; ++sc) {
                s8v bh = *(const s8v*)&sBh[cur][bbase + sc * 512 + roff];
                s8v bl = *(const s8v*)&sBl[cur][bbase + sc * 512 + roff];
                acc[sr][sc] = __builtin_amdgcn_mfma_f32_16x16x32_bf16(ah, bh, acc[sr][sc], 0, 0, 0);
                acc[sr][sc] = __builtin_amdgcn_mfma_f32_16x16x32_bf16(al, bh, acc[sr][sc], 0, 0, 0);
                acc[sr][sc] = __builtin_amdgcn_mfma_f32_16x16x32_bf16(ah, bl, acc[sr][sc], 0, 0, 0);
            }
        }
        if (k0 + 32 < 512) {
            LSTORE(cur ^ 1);
            if (k0 + 64 < 512) GLOAD(k0 + 64);
            __syncthreads();
        }
    }
#undef GLOAD
#undef LSTORE
    // C/D frag layout (m89): col = lane&15, row = (lane>>4)*4 + j
    const int crow = row0 + (wave & 1) * 64;
    const int ccol = col0 + (wave >> 1) * 64;
#pragma unroll
    for (int sr = 0; sr < 4; ++sr) {
        int rbase = crow + sr * 16 + ((lane >> 4) << 2);
#pragma unroll
        for (int sc = 0; sc < 4; ++sc) {
            int col = ccol + sc * 16 + (lane & 15);
            float bb = bias[col];
#pragma unroll
            for (int j = 0; j < 4; ++j) {
                int r = rbase + j;
                if (r < M) C[(size_t)r * 512 + col] = acc[sr][sc][j] + bb;
            }
        }
    }
}

// ================= CSR build (once per launch; graph shared by both layers) =================

__global__ void hist_kernel(const int* __restrict__ edst, int* __restrict__ deg, int E, int Etot) {
    int e = blockIdx.x * blockDim.x + threadIdx.x;
    if (e >= Etot) return;
    int dst = (e < E) ? edst[e] : (e - E);
    atomicAdd(&deg[dst], 1);
}

// parallel 3-phase exclusive scan: per-block scan -> block-offset scan -> add
__global__ void scan1_kernel(const int* __restrict__ deg, int* __restrict__ rowstart,
                             int* __restrict__ bsum, int n) {
    __shared__ int buf[256];
    int i = blockIdx.x * 256 + (int)threadIdx.x;
    int v = (i < n) ? deg[i] : 0;
    buf[threadIdx.x] = v;
    __syncthreads();
    for (int off = 1; off < 256; off <<= 1) {
        int t = (threadIdx.x >= (unsigned)off) ? buf[threadIdx.x - off] : 0;
        __syncthreads();
        buf[threadIdx.x] += t;
        __syncthreads();
    }
    if (i < n) rowstart[i] = buf[threadIdx.x] - v;   // exclusive within block
    if (threadIdx.x == 255) bsum[blockIdx.x] = buf[255];
}

__global__ __launch_bounds__(1024) void scan2_kernel(int* __restrict__ bsum,
                                                     int* __restrict__ boff,
                                                     int nb, int* __restrict__ total_out) {
    __shared__ int buf[1024];
    int v = ((int)threadIdx.x < nb) ? bsum[threadIdx.x] : 0;
    buf[threadIdx.x] = v;
    __syncthreads();
    for (int off = 1; off < 1024; off <<= 1) {
        int t = (threadIdx.x >= (unsigned)off) ? buf[threadIdx.x - off] : 0;
        __syncthreads();
        buf[threadIdx.x] += t;
        __syncthreads();
    }
    if ((int)threadIdx.x < nb) boff[threadIdx.x] = buf[threadIdx.x] - v;
    if (threadIdx.x == 1023) *total_out = buf[1023];
}

__global__ void scan3_kernel(int* __restrict__ rowstart, const int* __restrict__ boff, int n) {
    int i = blockIdx.x * 256 + (int)threadIdx.x;
    if (i < n) rowstart[i] += boff[blockIdx.x];
}

__global__ void scatter_kernel(const int* __restrict__ esrc, const int* __restrict__ edst,
                               const int* __restrict__ rowstart, int* __restrict__ cursor,
                               int* __restrict__ s_src, int E, int Etot) {
    int e = blockIdx.x * blockDim.x + threadIdx.x;
    if (e >= Etot) return;
    int src = (e < E) ? esrc[e] : (e - E);
    int dst = (e < E) ? edst[e] : (e - E);
    int pos = rowstart[dst] + atomicAdd(&cursor[dst], 1);
    s_src[pos] = src;
}

// ---- fused GATv2 edge phase: ONE wave per node handles all 4 heads ----
// lane owns 8 channels (2x float4); head = lane>>4; score reduce = 4-stage
// shfl_xor within the 16-lane head group. 2-edge pairs + 4-edge prefetch.
__global__ __launch_bounds__(256) void gat_fused_kernel(
        const float* __restrict__ xl, const float* __restrict__ xr,
        const float* __restrict__ att,
        const int* __restrict__ rowstart, const int* __restrict__ s_src,
        float* __restrict__ out, int n) {
    int node = blockIdx.x * 4 + (int)(threadIdx.x >> 6);
    if (node >= n) return;
    int lane = threadIdx.x & 63;
    int c0 = lane << 3;   // 8 channels
    const float4* xr4 = (const float4*)(xr + (size_t)node * HCD + c0);
    float4 r0 = xr4[0], r1 = xr4[1];
    const float4* at4 = (const float4*)(att + c0);
    float4 a0 = at4[0], a1 = at4[1];
    int beg = rowstart[node];
    int end = rowstart[node + 1];
    float m = -3.0e38f, den = 0.f;
    float4 acc0 = make_float4(0.f, 0.f, 0.f, 0.f);
    float4 acc1 = make_float4(0.f, 0.f, 0.f, 0.f);

#define SCORE(s, X0, X1)                                                       \
    {                                                                          \
        float t;                                                               \
        s = 0.f;                                                               \
        t = X0.x + r0.x; t = (t > 0.f) ? t : SLOPE * t; s = fmaf(t, a0.x, s);  \
        t = X0.y + r0.y; t = (t > 0.f) ? t : SLOPE * t; s = fmaf(t, a0.y, s);  \
        t = X0.z + r0.z; t = (t > 0.f) ? t : SLOPE * t; s = fmaf(t, a0.z, s);  \
        t = X0.w + r0.w; t = (t > 0.f) ? t : SLOPE * t; s = fmaf(t, a0.w, s);  \
        t = X1.x + r1.x; t = (t > 0.f) ? t : SLOPE * t; s = fmaf(t, a1.x, s);  \
        t = X1.y + r1.y; t = (t > 0.f) ? t : SLOPE * t; s = fmaf(t, a1.y, s);  \
        t = X1.z + r1.z; t = (t > 0.f) ? t : SLOPE * t; s = fmaf(t, a1.z, s);  \
        t = X1.w + r1.w; t = (t > 0.f) ? t : SLOPE * t; s = fmaf(t, a1.w, s);  \
    }

    int j = beg;
    float4 qa0, qa1, qb0, qb1, qc0, qc1, qd0, qd1;
    {
        const float4* p = (const float4*)(xl + (size_t)s_src[j] * HCD + c0);
        qa0 = p[0]; qa1 = p[1];
    }
    if (j + 1 < end) {
        const float4* p = (const float4*)(xl + (size_t)s_src[j + 1] * HCD + c0);
        qb0 = p[0]; qb1 = p[1];
    }
    if (j + 2 < end) {
        const float4* p = (const float4*)(xl + (size_t)s_src[j + 2] * HCD + c0);
        qc0 = p[0]; qc1 = p[1];
    }
    if (j + 3 < end) {
        const float4* p = (const float4*)(xl + (size_t)s_src[j + 3] * HCD + c0);
        qd0 = p[0]; qd1 = p[1];
    }

    while (j + 1 < end) {
        float4 A0 = qa0, A1 = qa1, B0 = qb0, B1 = qb1;
        qa0 = qc0; qa1 = qc1; qb0 = qd0; qb1 = qd1;
        if (j + 4 < end) {
            const float4* p = (const float4*)(xl + (size_t)s_src[j + 4] * HCD + c0);
            qc0 = p[0]; qc1 = p[1];
        }
        if (j + 5 < end) {
            const float4* p = (const float4*)(xl + (size_t)s_src[j + 5] * HCD + c0);
            qd0 = p[0]; qd1 = p[1];
        }
        float sA, sB;
        SCORE(sA, A0, A1);
        SCORE(sB, B0, B1);
        // 4-stage reduce within 16-lane head group (interleaved for ILP)
#pragma unroll
        for (int k = 1; k < 16; k <<= 1) {
            sA += __shfl_xor(sA, k);
            sB += __shfl_xor(sB, k);
        }
        float mn = fmaxf(m, fmaxf(sA, sB));
        float sc = expf(m - mn);
        float pA = expf(sA - mn);
        float pB = expf(sB - mn);
        den = fmaf(den, sc, pA + pB);
        acc0.x = fmaf(acc0.x, sc, fmaf(pA, A0.x, pB * B0.x));
        acc0.y = fmaf(acc0.y, sc, fmaf(pA, A0.y, pB * B0.y));
        acc0.z = fmaf(acc0.z, sc, fmaf(pA, A0.z, pB * B0.z));
        acc0.w = fmaf(acc0.w, sc, fmaf(pA, A0.w, pB * B0.w));
        acc1.x = fmaf(acc1.x, sc, fmaf(pA, A1.x, pB * B1.x));
        acc1.y = fmaf(acc1.y, sc, fmaf(pA, A1.y, pB * B1.y));
        acc1.z = fmaf(acc1.z, sc, fmaf(pA, A1.z, pB * B1.z));
        acc1.w = fmaf(acc1.w, sc, fmaf(pA, A1.w, pB * B1.w));
        m = mn;
        j += 2;
    }
    if (j < end) {   // odd tail
        float4 A0 = qa0, A1 = qa1;
        float sA;
        SCORE(sA, A0, A1);
#pragma unroll
        for (int k = 1; k < 16; k <<= 1) sA += __shfl_xor(sA, k);
        float mn = fmaxf(m, sA);
        float sc = expf(m - mn);
        float pA = expf(sA - mn);
        den = fmaf(den, sc, pA);
        acc0.x = fmaf(acc0.x, sc, pA * A0.x);
        acc0.y = fmaf(acc0.y, sc, pA * A0.y);
        acc0.z = fmaf(acc0.z, sc, pA * A0.z);
        acc0.w = fmaf(acc0.w, sc, pA * A0.w);
        acc1.x = fmaf(acc1.x, sc, pA * A1.x);
        acc1.y = fmaf(acc1.y, sc, pA * A1.y);
        acc1.z = fmaf(acc1.z, sc, pA * A1.z);
        acc1.w = fmaf(acc1.w, sc, pA * A1.w);
    }
#undef SCORE
    float inv = 1.0f / (den + 1e-16f);
    float4* o = (float4*)(out + (size_t)node * HCD + c0);
    o[0] = make_float4(acc0.x * inv, acc0.y * inv, acc0.z * inv, acc0.w * inv);
    o[1] = make_float4(acc1.x * inv, acc1.y * inv, acc1.z * inv, acc1.w * inv);
}

// ---- BatchNorm statistics: per-channel sum and sum-of-squares ----
__global__ void bn_stats_kernel(const float* __restrict__ h, float* __restrict__ sum,
                                float* __restrict__ sumsq, int n) {
    int c = blockIdx.y * blockDim.x + threadIdx.x;   // 0..511
    int r0 = blockIdx.x * 128;
    int r1 = min(r0 + 128, n);
    float s = 0.f, s2 = 0.f;
    for (int r = r0; r < r1; ++r) {
        float v = h[(size_t)r * HCD + c];
        s += v;
        s2 = fmaf(v, v, s2);
    }
    atomicAdd(&sum[c], s);
    atomicAdd(&sumsq[c], s2);
}

__global__ void bn_finalize_kernel(const float* __restrict__ sum, const float* __restrict__ sumsq,
                                   const float* __restrict__ g, const float* __restrict__ b,
                                   float* __restrict__ scale, float* __restrict__ shift, int n) {
    int c = threadIdx.x;   // 512
    float inv_n = 1.0f / (float)n;
    float mu = sum[c] * inv_n;
    float var = fmaxf(sumsq[c] * inv_n - mu * mu, 0.0f);
    float sc = g[c] * rsqrtf(var + EPS_BN);
    scale[c] = sc;
    shift[c] = b[c] - mu * sc;
}

// ---- per-graph mean pool, row-chunk parallel (batch is sorted) ----
__device__ __forceinline__ int lower_bound_i(const int* __restrict__ a, int n, int key) {
    int lo = 0, hi = n;
    while (lo < hi) {
        int mid = (lo + hi) >> 1;
        if (a[mid] < key) lo = mid + 1; else hi = mid;
    }
    return lo;
}

// grid (b, PSPLIT): partial BN2+ReLU sums atomically accumulated into pooled (pre-zeroed)
__global__ void pool_partial_kernel(const float* __restrict__ h, const int* __restrict__ batch,
                                    const float* __restrict__ scale, const float* __restrict__ shift,
                                    float* __restrict__ pooled, int n) {
    int g = blockIdx.x;
    int chunk = blockIdx.y;
    int c = threadIdx.x;   // 512
    int start = lower_bound_i(batch, n, g);
    int end   = lower_bound_i(batch, n, g + 1);
    int len = end - start;
    int cs = start + (int)(((long long)len * chunk) / PSPLIT);
    int ce = start + (int)(((long long)len * (chunk + 1)) / PSPLIT);
    if (cs >= ce) return;
    float sc = scale[c], sh = shift[c];
    float s = 0.f;
    for (int r = cs; r < ce; ++r)
        s += fmaxf(fmaf(h[(size_t)r * HCD + c], sc, sh), 0.f);
    atomicAdd(&pooled[(size_t)g * HCD + c], s);
}

// ---- MLP head: relu([pooled_sum/cnt | gfeat] @ fc1 + b1) @ fc2 + b2 ----
__global__ void head_kernel(const float* __restrict__ pooled, const float* __restrict__ gfeat,
                            const int* __restrict__ batch,
                            const float* __restrict__ fc1w, const float* __restrict__ fc1b,
                            const float* __restrict__ fc2w, const float* __restrict__ fc2b,
                            float* __restrict__ out, int gdim, int n) {
    int g = blockIdx.x;
    int j = threadIdx.x;   // 128
    int start = lower_bound_i(batch, n, g);
    int end   = lower_bound_i(batch, n, g + 1);
    float icnt = 1.0f / (float)max(end - start, 1);
    float acc = fc1b[j];
    const float* prow = pooled + (size_t)g * HCD;
    for (int i = 0; i < HCD; ++i) acc = fmaf(prow[i] * icnt, fc1w[i * CCH + j], acc);
    const float* grow = gfeat + (size_t)g * gdim;
    for (int i = 0; i < gdim; ++i) acc = fmaf(grow[i], fc1w[(HCD + i) * CCH + j], acc);
    acc = fmaxf(acc, 0.f);
    __shared__ float z[CCH];
    z[j] = acc * fc2w[j];
    __syncthreads();
    for (int s = CCH / 2; s > 0; s >>= 1) {
        if (j < s) z[j] += z[j + s];
        __syncthreads();
    }
    if (j == 0) out[g] = z[0] + fc2b[0];
}

extern "C" void kernel_launch(void* const* d_in, const int* in_sizes, int n_in,
                              void* d_out, int out_size, void* d_ws, size_t ws_size,
                              hipStream_t stream) {
    const float* x     = (const float*)d_in[0];
    const float* gfeat = (const float*)d_in[1];
    const float* W1l   = (const float*)d_in[2];
    const float* b1l   = (const float*)d_in[3];
    const float* W1r   = (const float*)d_in[4];
    const float* b1r   = (const float*)d_in[5];
    const float* att1  = (const float*)d_in[6];
    // d_in[7] = bias1: cancels through BN
    const float* W2l   = (const float*)d_in[8];
    const float* b2l   = (const float*)d_in[9];
    const float* W2r   = (const float*)d_in[10];
    const float* b2r   = (const float*)d_in[11];
    const float* att2  = (const float*)d_in[12];
    // d_in[13] = bias2: cancels through BN
    const float* bn1_g = (const float*)d_in[14];
    const float* bn1_b = (const float*)d_in[15];
    const float* bn2_g = (const float*)d_in[16];
    const float* bn2_b = (const float*)d_in[17];
    const float* fc1w  = (const float*)d_in[18];
    const float* fc1b  = (const float*)d_in[19];
    const float* fc2w  = (const float*)d_in[20];
    const float* fc2b  = (const float*)d_in[21];
    const int* eidx    = (const int*)d_in[22];
    const int* batch   = (const int*)d_in[23];

    const int n    = in_sizes[0] / 9;
    const int E    = in_sizes[22] / 2;
    const int Etot = E + n;
    const int b    = out_size;
    const int gdim = in_sizes[1] / b;
    const int* esrc = eidx;
    const int* edst = eidx + E;

    float* ws = (float*)d_ws;
    size_t nHC = (size_t)n * HCD;
    float* xl      = ws;
    float* xr      = xl + nHC;
    float* hbuf    = xr + nHC;
    int* deg       = (int*)(hbuf + nHC);     // n
    int* rowstart  = deg + n;                // n+1
    int* cursor    = rowstart + n + 1;       // n
    int* bsum      = cursor + n;             // 1024
    int* boff      = bsum + 1024;            // 1024
    int* s_src     = boff + 1024;            // Etot
    float* bnsum   = (float*)(s_src + Etot); // 512
    float* bnsumsq = bnsum + HCD;            // 512
    float* bnscale = bnsumsq + HCD;          // 512
    float* bnshift = bnscale + HCD;          // 512
    float* pooled  = bnshift + HCD;          // b*512
    unsigned short* Ah   = (unsigned short*)(pooled + (size_t)b * HCD);  // n*512 bf16
    unsigned short* Al   = Ah + nHC;
    unsigned short* BThl = Al + nHC;         // 512*512 each
    unsigned short* BTll = BThl + HCD * HCD;
    unsigned short* BThr = BTll + HCD * HCD;
    unsigned short* BTlr = BThr + HCD * HCD;

    const int BLK = 256;
    const int linBlocks  = (int)((nHC + BLK - 1) / BLK);
    const int eBlocks    = (Etot + BLK - 1) / BLK;
    const int bnxBlocks  = (n + 127) / 128;
    const int saBlocks   = (int)((nHC / 4 + BLK - 1) / BLK);
    const int nrt        = (n + 127) / 128;
    const int scBlocks   = (n + 255) / 256;      // <= 1024 for n <= 262144
    const int gatBlocks  = (n + 3) / 4;
    dim3 gemmGrid(nrt * 8);

    // ---------------- CSR build (shared by both layers) ----------------
    hipMemsetAsync(deg, 0, (size_t)(2 * n + 1) * sizeof(int), stream);
    hipMemsetAsync(cursor, 0, (size_t)n * sizeof(int), stream);
    hist_kernel<<<eBlocks, BLK, 0, stream>>>(edst, deg, E, Etot);
    scan1_kernel<<<scBlocks, 256, 0, stream>>>(deg, rowstart, bsum, n);
    scan2_kernel<<<1, 1024, 0, stream>>>(bsum, boff, scBlocks, rowstart + n);
    scan3_kernel<<<scBlocks, 256, 0, stream>>>(rowstart, boff, n);
    scatter_kernel<<<eBlocks, BLK, 0, stream>>>(esrc, edst, rowstart, cursor, s_src, E, Etot);
    // weight split/transpose (graph-independent)
    splitBT_kernel<<<(HCD * HCD) / BLK, BLK, 0, stream>>>(W2l, W2r, BThl, BTll, BThr, BTlr);

    // ---------------- layer 1 ----------------
    lin1_kernel<<<linBlocks, BLK, 0, stream>>>(x, W1l, b1l, W1r, b1r, xl, xr, n);
    gat_fused_kernel<<<gatBlocks, 256, 0, stream>>>(xl, xr, att1, rowstart, s_src, hbuf, n);
    hipMemsetAsync(bnsum, 0, HCD * 2 * sizeof(float), stream);
    bn_stats_kernel<<<dim3(bnxBlocks, 2), BLK, 0, stream>>>(hbuf, bnsum, bnsumsq, n);
    bn_finalize_kernel<<<1, HCD, 0, stream>>>(bnsum, bnsumsq, bn1_g, bn1_b, bnscale, bnshift, n);

    // ---------------- layer 2: BN1+ReLU fused into split; MFMA GEMM ----------------
    splitA_kernel<<<saBlocks, BLK, 0, stream>>>(hbuf, bnscale, bnshift, Ah, Al, (int)(nHC / 4));
    gemm_mfma_kernel<<<gemmGrid, BLK, 0, stream>>>(Ah, Al, BThl, BTll, BThr, BTlr,
                                                   b2l, b2r, xl, xr, n);
    gat_fused_kernel<<<gatBlocks, 256, 0, stream>>>(xl, xr, att2, rowstart, s_src, hbuf, n);
    hipMemsetAsync(bnsum, 0, HCD * 2 * sizeof(float), stream);
    bn_stats_kernel<<<dim3(bnxBlocks, 2), BLK, 0, stream>>>(hbuf, bnsum, bnsumsq, n);
    bn_finalize_kernel<<<1, HCD, 0, stream>>>(bnsum, bnsumsq, bn2_g, bn2_b, bnscale, bnshift, n);

    // ---------------- readout (BN2+ReLU fused into chunked pool) ----------------
    hipMemsetAsync(pooled, 0, (size_t)b * HCD * sizeof(float), stream);
    pool_partial_kernel<<<dim3(b, PSPLIT), HCD, 0, stream>>>(hbuf, batch, bnscale, bnshift, pooled, n);
    head_kernel<<<b, CCH, 0, stream>>>(pooled, gfeat, batch, fc1w, fc1b, fc2w, fc2b,
                                       (float*)d_out, gdim, n);
}